// Round 9
// baseline (317.242 us; speedup 1.0000x reference)
//
#include <hip/hip_runtime.h>
#include <hip/hip_bf16.h>
#include <hip/hip_cooperative_groups.h>

namespace cg = cooperative_groups;

// Problem dims (fixed): B=8, L=128, H=768, R=24
#define BD   8
#define LD   128
#define HD   768
#define RD   24
#define H2D  384
#define NF   1536   // fused N (two heads side by side)
#define WSZ  589824 // 768*768

typedef __attribute__((ext_vector_type(8))) short bf16x8;
typedef __attribute__((ext_vector_type(4))) float f32x4;

__device__ __forceinline__ short f2bf(float f) {
    __hip_bfloat16 h = __float2bfloat16(f);
    return *reinterpret_cast<short*>(&h);
}

struct KParams {
    const float *embed, *mask;
    const int *trel;
    const float *W_hr, *b_hr, *W_rj, *b_rj, *rel_emb, *W_corr;
    const float *b_corr, *W_gc, *b_gc;
    const float *W_sh, *b_sh, *W_st, *b_st, *W_oh, *b_oh, *W_ot, *b_ot;
    float *AC, *biasrel, *rh, *pool;
    unsigned short *embedB, *WT;
    float *out_stage1, *out_subj, *out_obj, *out_corr;
};

union SMem {
    struct { float mrow[LD]; float msum; float part[4][64]; } pl;
    struct { float re[HD]; float part2[2][128]; } br;
    float tile[64 * 65];
    struct __align__(16) { short As[64][40]; short Bs0[64][40]; short Bs1[64][40];
                           float partial[64][3]; } gm;
    struct { float prow[HD]; float rpart[4][64]; } rl;
    struct { float rlb[H2D]; float spart[8][RD]; } st;
};

// ---------------------------------------------------------------------------
// prep unit q in [0,864):
//   [0,96) pool | [96,192) biasrel (+subj/obj bias init) | [192,288) embed->bf16
//   [288,864) W 64x64 transpose+convert (w = (q-288)/144)
__device__ void prep_unit(const KParams& p, SMem& sm, int q, int tid) {
    if (q < 96) {
        const int b = q / 12, c = q % 12;
        if (tid < LD) sm.pl.mrow[tid] = p.mask[b * LD + tid];
        __syncthreads();
        if (tid == 0) {
            float s = 0.f;
            for (int l = 0; l < LD; ++l) s += sm.pl.mrow[l];
            sm.pl.msum = s;
        }
        __syncthreads();
        const int lc = tid >> 6, hh = tid & 63;
        const int h = c * 64 + hh;
        float acc = 0.f;
        const float* base = p.embed + ((size_t)b * LD + lc * 32) * HD + h;
#pragma unroll 8
        for (int i = 0; i < 32; ++i) acc += base[(size_t)i * HD] * sm.pl.mrow[lc * 32 + i];
        sm.pl.part[lc][hh] = acc;
        __syncthreads();
        if (lc == 0)
            p.pool[b * HD + h] = (sm.pl.part[0][hh] + sm.pl.part[1][hh] +
                                  sm.pl.part[2][hh] + sm.pl.part[3][hh]) / sm.pl.msum;
    } else if (q < 192) {
        const int qq = q - 96;
        const int b = qq / 12, cc = qq % 12;
        const int rel = p.trel[b];
        for (int k = tid; k < HD; k += 256) sm.br.re[k] = p.rel_emb[(size_t)rel * HD + k];
        if (cc == 0) {
            for (int u = tid; u < 3 * LD; u += 256) {
                const int l = u / 3, t = u - 3 * l;
                p.out_subj[(b * LD + l) * 3 + t] = p.b_st[t];
                p.out_obj [(b * LD + l) * 3 + t] = p.b_ot[t];
            }
        }
        __syncthreads();
        const int kc = tid >> 7, nn = tid & 127;
        const int n = cc * 128 + nn;
        const float* Wp; float bb; int col;
        if (n < HD) { Wp = p.W_sh; bb = p.b_sh[n];      col = n; }
        else        { Wp = p.W_oh; bb = p.b_oh[n - HD]; col = n - HD; }
        float acc = 0.f;
#pragma unroll 8
        for (int i = 0; i < 384; ++i) {
            const int k = kc * 384 + i;
            acc += sm.br.re[k] * Wp[(size_t)k * HD + col];
        }
        sm.br.part2[kc][nn] = acc;
        __syncthreads();
        if (kc == 0) p.biasrel[b * NF + n] = sm.br.part2[0][nn] + sm.br.part2[1][nn] + bb;
    } else if (q < 288) {
        const int base = (q - 192) * 8192;
#pragma unroll
        for (int it = 0; it < 4; ++it) {
            const int off = base + it * 2048 + tid * 8;
            float4 v0 = *(const float4*)&p.embed[off];
            float4 v1 = *(const float4*)&p.embed[off + 4];
            bf16x8 pk;
            pk[0] = f2bf(v0.x); pk[1] = f2bf(v0.y); pk[2] = f2bf(v0.z); pk[3] = f2bf(v0.w);
            pk[4] = f2bf(v1.x); pk[5] = f2bf(v1.y); pk[6] = f2bf(v1.z); pk[7] = f2bf(v1.w);
            *(bf16x8*)&p.embedB[off] = pk;
        }
    } else {
        const int qq = q - 288;
        const int w = qq / 144, t = qq % 144;
        const int kt = t / 12, nt = t % 12;
        const float* src = (w == 0) ? p.W_corr
                         : (w == 1) ? p.W_corr + WSZ
                         : (w == 2) ? p.W_sh + WSZ
                                    : p.W_oh + WSZ;
        unsigned short* dst = p.WT + (size_t)w * WSZ;
        const int r = tid >> 2, c4 = (tid & 3) * 16;
#pragma unroll
        for (int i = 0; i < 4; ++i) {
            float4 v = *(const float4*)&src[(size_t)(kt * 64 + r) * HD + nt * 64 + c4 + i * 4];
            sm.tile[r * 65 + c4 + i * 4 + 0] = v.x;
            sm.tile[r * 65 + c4 + i * 4 + 1] = v.y;
            sm.tile[r * 65 + c4 + i * 4 + 2] = v.z;
            sm.tile[r * 65 + c4 + i * 4 + 3] = v.w;
        }
        __syncthreads();
        bf16x8 p0, p1;
#pragma unroll
        for (int j = 0; j < 8; ++j) {
            p0[j] = f2bf(sm.tile[(c4 + j) * 65 + r]);
            p1[j] = f2bf(sm.tile[(c4 + 8 + j) * 65 + r]);
        }
        unsigned short* o = dst + (size_t)(nt * 64 + r) * HD + kt * 64 + c4;
        *(bf16x8*)(o)     = p0;
        *(bf16x8*)(o + 8) = p1;
    }
}

// ---------------------------------------------------------------------------
// GEMM unit u in [0,384): dual MFMA GEMM, 64x64 tile
__device__ void gemm_unit(const KParams& p, SMem& sm, int u, int tid) {
    const int bn0 = (u % 24) * 64;
    const int bm0 = (u / 24) * 64;

    const unsigned short* W0 = (bn0 < HD) ? p.WT : p.WT + WSZ;
    const unsigned short* W1 = (bn0 < HD) ? p.WT + 2 * (size_t)WSZ : p.WT + 3 * (size_t)WSZ;
    const int col0 = (bn0 < HD) ? bn0 : bn0 - HD;

    if (tid < 192) sm.gm.partial[tid / 3][tid % 3] = 0.f;

    const int row = tid >> 2;
    const int kc8 = (tid & 3) * 8;
    const int lane = tid & 63;
    const int wv = tid >> 6;
    const int wm = (wv >> 1) * 32;
    const int wn = (wv & 1) * 32;
    const int fr = lane & 15;
    const int kq = (lane >> 4) * 8;
    const int mq = (lane >> 4) * 4;

    f32x4 c00 = {0.f,0.f,0.f,0.f}, c01 = c00, c10 = c00, c11 = c00;
    f32x4 h00 = c00, h01 = c00, h10 = c00, h11 = c00;

    for (int kt = 0; kt < 24; ++kt) {
        const int k0 = kt << 5;
        bf16x8 av  = *(const bf16x8*)&p.embedB[(size_t)(bm0 + row) * HD + k0 + kc8];
        bf16x8 b0v = *(const bf16x8*)&W0[(size_t)(col0 + row) * HD + k0 + kc8];
        bf16x8 b1v = *(const bf16x8*)&W1[(size_t)(col0 + row) * HD + k0 + kc8];

        __syncthreads();
        *(bf16x8*)&sm.gm.As [row][kc8] = av;
        *(bf16x8*)&sm.gm.Bs0[row][kc8] = b0v;
        *(bf16x8*)&sm.gm.Bs1[row][kc8] = b1v;
        __syncthreads();

        bf16x8 a0 = *(bf16x8*)&sm.gm.As[wm + fr][kq];
        bf16x8 a1 = *(bf16x8*)&sm.gm.As[wm + 16 + fr][kq];
        bf16x8 b0 = *(bf16x8*)&sm.gm.Bs0[wn + fr][kq];
        bf16x8 b1 = *(bf16x8*)&sm.gm.Bs0[wn + 16 + fr][kq];
        bf16x8 d0 = *(bf16x8*)&sm.gm.Bs1[wn + fr][kq];
        bf16x8 d1 = *(bf16x8*)&sm.gm.Bs1[wn + 16 + fr][kq];
        c00 = __builtin_amdgcn_mfma_f32_16x16x32_bf16(a0, b0, c00, 0, 0, 0);
        c01 = __builtin_amdgcn_mfma_f32_16x16x32_bf16(a0, b1, c01, 0, 0, 0);
        c10 = __builtin_amdgcn_mfma_f32_16x16x32_bf16(a1, b0, c10, 0, 0, 0);
        c11 = __builtin_amdgcn_mfma_f32_16x16x32_bf16(a1, b1, c11, 0, 0, 0);
        h00 = __builtin_amdgcn_mfma_f32_16x16x32_bf16(a0, d0, h00, 0, 0, 0);
        h01 = __builtin_amdgcn_mfma_f32_16x16x32_bf16(a0, d1, h01, 0, 0, 0);
        h10 = __builtin_amdgcn_mfma_f32_16x16x32_bf16(a1, d0, h10, 0, 0, 0);
        h11 = __builtin_amdgcn_mfma_f32_16x16x32_bf16(a1, d1, h11, 0, 0, 0);
    }

    // GEMM0 epilogue: C/D layout col=lane&15, row=(lane>>4)*4+reg [m89/m91]
#pragma unroll
    for (int i = 0; i < 2; ++i) {
#pragma unroll
        for (int j = 0; j < 2; ++j) {
            f32x4 a = (i == 0) ? (j == 0 ? c00 : c01) : (j == 0 ? c10 : c11);
            const int ncol = bn0 + wn + j * 16 + fr;
#pragma unroll
            for (int r = 0; r < 4; ++r) {
                const int mrow = bm0 + wm + i * 16 + mq + r;
                p.AC[(size_t)mrow * NF + ncol] = a[r];
            }
        }
    }

    // GEMM1 epilogue: relu(+biasrel), row-dot W_st/W_ot, atomics
    {
        const float* brl = p.biasrel + (size_t)(bm0 / LD) * NF;
        const float* Wt = (bn0 < HD) ? p.W_st : p.W_ot;
        float* op = (bn0 < HD) ? p.out_subj : p.out_obj;
        float pt[8][3] = {};
#pragma unroll
        for (int j = 0; j < 2; ++j) {
            const int ncol = bn0 + wn + j * 16 + fr;
            const int ncl = (bn0 < HD) ? ncol : ncol - HD;
            const float wt0 = Wt[ncl * 3 + 0];
            const float wt1 = Wt[ncl * 3 + 1];
            const float wt2 = Wt[ncl * 3 + 2];
            const float bias = brl[ncol];
#pragma unroll
            for (int i = 0; i < 2; ++i) {
                f32x4 a = (i == 0) ? (j == 0 ? h00 : h01) : (j == 0 ? h10 : h11);
#pragma unroll
                for (int r = 0; r < 4; ++r) {
                    const float v = fmaxf(a[r] + bias, 0.f);
                    pt[i * 4 + r][0] += v * wt0;
                    pt[i * 4 + r][1] += v * wt1;
                    pt[i * 4 + r][2] += v * wt2;
                }
            }
        }
#pragma unroll
        for (int mask = 1; mask < 16; mask <<= 1) {
#pragma unroll
            for (int x = 0; x < 8; ++x)
#pragma unroll
                for (int t = 0; t < 3; ++t)
                    pt[x][t] += __shfl_xor(pt[x][t], mask, 64);
        }
        if (fr == 0) {
#pragma unroll
            for (int i = 0; i < 2; ++i)
#pragma unroll
                for (int r = 0; r < 4; ++r)
#pragma unroll
                    for (int t = 0; t < 3; ++t)
                        atomicAdd(&sm.gm.partial[wm + i * 16 + mq + r][t], pt[i * 4 + r][t]);
        }
        __syncthreads();
        if (tid < 192) {
            const int m = tid / 3, t = tid % 3;
            atomicAdd(&op[(size_t)(bm0 + m) * 3 + t], sm.gm.partial[m][t]);
        }
    }
}

// ---------------------------------------------------------------------------
// relh unit u in [0,48): rh[b,n] = relu(pool@W_hr + b_hr), 64 n's
__device__ void relh_unit(const KParams& p, SMem& sm, int u, int tid) {
    const int b = u / 6, c = u % 6;
    for (int k = tid; k < HD; k += 256) sm.rl.prow[k] = p.pool[b * HD + k];
    __syncthreads();
    const int kc = tid >> 6, nn = tid & 63;
    const int n = c * 64 + nn;
    float acc = 0.f;
#pragma unroll 8
    for (int i = 0; i < 192; ++i) {
        const int k = kc * 192 + i;
        acc += sm.rl.prow[k] * p.W_hr[(size_t)k * H2D + n];
    }
    sm.rl.rpart[kc][nn] = acc;
    __syncthreads();
    if (kc == 0)
        p.rh[b * H2D + n] = fmaxf(sm.rl.rpart[0][nn] + sm.rl.rpart[1][nn] +
                                  sm.rl.rpart[2][nn] + sm.rl.rpart[3][nn] + p.b_hr[n], 0.f);
}

// ---------------------------------------------------------------------------
// corres unit u in [0,256): b = u>>5, i0 = (u&31)*4; 256 threads (4 waves)
__device__ void corres_unit(const KParams& p, int u, int tid) {
    const int b = u >> 5;
    const int i0 = (u & 31) * 4;
    const int lane = tid & 63;
    const int wave = tid >> 6;  // 0..3

    f32x4 wg[3], cb[4][3];
#pragma unroll
    for (int s = 0; s < 3; ++s) {
        const int h = s * 256 + lane * 4;
        f32x4 w  = *(const f32x4*)&p.W_gc[h];
        f32x4 bc = *(const f32x4*)&p.b_corr[h];
        wg[s] = w;
#pragma unroll
        for (int i = 0; i < 4; ++i) {
            f32x4 cv = *(const f32x4*)&p.AC[((size_t)(b * LD + i0 + i)) * NF + HD + h];
            cb[i][s] = cv + bc;
        }
    }
    const float bg = p.b_gc[0];

    // software-pipelined over j (stride 4): prefetch next A row
    f32x4 a[3];
    {
        const float* ar = p.AC + ((size_t)(b * LD + wave)) * NF;
#pragma unroll
        for (int s = 0; s < 3; ++s) a[s] = *(const f32x4*)&ar[s * 256 + lane * 4];
    }
    for (int j = wave; j < LD; j += 4) {
        f32x4 an[3];
        if (j + 4 < LD) {
            const float* ar = p.AC + ((size_t)(b * LD + j + 4)) * NF;
#pragma unroll
            for (int s = 0; s < 3; ++s) an[s] = *(const f32x4*)&ar[s * 256 + lane * 4];
        }
        float sum[4] = {0.f, 0.f, 0.f, 0.f};
#pragma unroll
        for (int s = 0; s < 3; ++s) {
#pragma unroll
            for (int i = 0; i < 4; ++i) {
                f32x4 v = a[s] + cb[i][s];
#pragma unroll
                for (int t = 0; t < 4; ++t)
                    sum[i] += fmaxf(v[t], 0.f) * wg[s][t];
            }
        }
#pragma unroll
        for (int off = 32; off > 0; off >>= 1) {
#pragma unroll
            for (int i = 0; i < 4; ++i) sum[i] += __shfl_down(sum[i], off, 64);
        }
        if (lane == 0) {
#pragma unroll
            for (int i = 0; i < 4; ++i)
                p.out_corr[((size_t)(b * LD + i0 + i)) * LD + j] = sum[i] + bg;
        }
#pragma unroll
        for (int s = 0; s < 3; ++s) a[s] = an[s];
    }
}

// ---------------------------------------------------------------------------
// stage1 unit b in [0,8)
__device__ void stage1_unit(const KParams& p, SMem& sm, int b, int tid) {
    for (int k = tid; k < H2D; k += 256) sm.st.rlb[k] = p.rh[b * H2D + k];
    __syncthreads();
    if (tid < 8 * RD) {
        const int n = tid % RD, kc = tid / RD;
        float acc = 0.f;
#pragma unroll 8
        for (int i = 0; i < 48; ++i) {
            const int k = kc * 48 + i;
            acc += sm.st.rlb[k] * p.W_rj[k * RD + n];
        }
        sm.st.spart[kc][n] = acc;
    }
    __syncthreads();
    if (tid < RD) {
        float s = p.b_rj[tid];
#pragma unroll
        for (int q = 0; q < 8; ++q) s += sm.st.spart[q][tid];
        p.out_stage1[b * RD + tid] = s;
    }
}

// ---------------------------------------------------------------------------
// Cooperative mega-kernel: 256 blocks (fits co-residency even at 1 block/CU)
__global__ __launch_bounds__(256) void mega(KParams p) {
    __shared__ SMem sm;
    const int blk = blockIdx.x;
    const int tid = threadIdx.x;
    cg::grid_group grid = cg::this_grid();

    // Phase A: 864 prep units, strided
    prep_unit(p, sm, blk, tid);
    for (int q = blk + 256; q < 864; q += 256) {
        __syncthreads();
        prep_unit(p, sm, q, tid);
    }
    __threadfence();
    grid.sync();

    // Phase B: 384 GEMM + 48 relh units over 256 blocks
    if (blk < 384) gemm_unit(p, sm, blk, tid);
    else           relh_unit(p, sm, blk - 384, tid);   // unreachable (blk<256) but kept for clarity
    if (blk < 176) {
        __syncthreads();
        const int u2 = blk + 256;
        if (u2 < 384) gemm_unit(p, sm, u2, tid);
        else          relh_unit(p, sm, u2 - 384, tid);
    }
    __threadfence();
    grid.sync();

    // Phase C: stage1 (blocks 248..255) then corres (all 256 blocks)
    if (blk >= 248) stage1_unit(p, sm, blk - 248, tid);
    __syncthreads();
    corres_unit(p, blk, tid);
}

// ---------------------------------------------------------------------------
// Fallback pipeline (3 regular launches), used if cooperative launch fails
__global__ __launch_bounds__(256) void prep_k(KParams p) {
    __shared__ SMem sm;
    prep_unit(p, sm, blockIdx.x, threadIdx.x);
}
__global__ __launch_bounds__(256) void phaseB_k(KParams p) {
    __shared__ SMem sm;
    const int u = blockIdx.x;
    if (u < 384) gemm_unit(p, sm, u, threadIdx.x);
    else         relh_unit(p, sm, u - 384, threadIdx.x);
}
__global__ __launch_bounds__(256) void phaseC_k(KParams p) {
    __shared__ SMem sm;
    const int u = blockIdx.x;
    if (u < 256) corres_unit(p, u, threadIdx.x);
    else         stage1_unit(p, sm, u - 256, threadIdx.x);
}

// ---------------------------------------------------------------------------
extern "C" void kernel_launch(void* const* d_in, const int* in_sizes, int n_in,
                              void* d_out, int out_size, void* d_ws, size_t ws_size,
                              hipStream_t stream) {
    float* out = (float*)d_out;
    float* ws  = (float*)d_ws;

    KParams p;
    p.embed   = (const float*)d_in[0];
    p.mask    = (const float*)d_in[1];
    p.trel    = (const int*)d_in[2];
    p.W_hr    = (const float*)d_in[3];
    p.b_hr    = (const float*)d_in[4];
    p.W_rj    = (const float*)d_in[5];
    p.b_rj    = (const float*)d_in[6];
    p.rel_emb = (const float*)d_in[7];
    p.W_corr  = (const float*)d_in[8];
    p.b_corr  = (const float*)d_in[9];
    p.W_gc    = (const float*)d_in[10];
    p.b_gc    = (const float*)d_in[11];
    p.W_sh    = (const float*)d_in[12];
    p.b_sh    = (const float*)d_in[13];
    p.W_st    = (const float*)d_in[14];
    p.b_st    = (const float*)d_in[15];
    p.W_oh    = (const float*)d_in[16];
    p.b_oh    = (const float*)d_in[17];
    p.W_ot    = (const float*)d_in[18];
    p.b_ot    = (const float*)d_in[19];

    p.AC      = ws;                             // 1,572,864 floats
    p.biasrel = ws + 1572864;                   // 12,288
    p.rh      = ws + 1572864 + 12288;           // 3,072
    p.pool    = ws + 1572864 + 12288 + 3072;    // 6,144
    p.embedB  = (unsigned short*)(ws + 1594368);            // 786,432 shorts
    p.WT      = (unsigned short*)(ws + 1594368 + 393216);   // 4*589,824 shorts

    // Output layout: stage1[192] | subj[3072] | obj[3072] | pred_corres[131072]
    p.out_stage1 = out;
    p.out_subj   = out + 192;
    p.out_obj    = out + 3264;
    p.out_corr   = out + 6336;

    void* args[] = { (void*)&p };
    hipError_t e = hipLaunchCooperativeKernel((const void*)mega, dim3(256), dim3(256),
                                              args, 0u, stream);
    if (e != hipSuccess) {
        (void)hipGetLastError();  // clear error state
        prep_k<<<864, 256, 0, stream>>>(p);
        phaseB_k<<<432, 256, 0, stream>>>(p);
        phaseC_k<<<264, 256, 0, stream>>>(p);
    }
}

// Round 10
// 182.741 us; speedup vs baseline: 1.7360x; 1.7360x over previous
//
#include <hip/hip_runtime.h>
#include <hip/hip_bf16.h>

// Problem dims (fixed): B=8, L=128, H=768, R=24
#define BD   8
#define LD   128
#define HD   768
#define RD   24
#define H2D  384
#define NF   1536   // fused N (two heads side by side)
#define WSZ  589824 // 768*768

typedef __attribute__((ext_vector_type(8))) short bf16x8;
typedef __attribute__((ext_vector_type(4))) float f32x4;

__device__ __forceinline__ short f2bf(float f) {
    __hip_bfloat16 h = __float2bfloat16(f);
    return *reinterpret_cast<short*>(&h);
}

__device__ __forceinline__ f32x4 vmax0(f32x4 v) {
    f32x4 r;
    r[0] = fmaxf(v[0], 0.f); r[1] = fmaxf(v[1], 0.f);
    r[2] = fmaxf(v[2], 0.f); r[3] = fmaxf(v[3], 0.f);
    return r;
}

// ---------------------------------------------------------------------------
// Launch 1: prep. 864 blocks x 256 threads, flat blockIdx.x:
//   [0,96):    pool       (b = q/12, c = q%12; 4-way split over L)
//   [96,192):  biasrel    = re@Wtop + bias (2-way split-K); q==96 inits subj/obj
//   [192,288): embed fp32 -> bf16 (row-major, no transpose)
//   [288,864): W 64x64 tile transpose+convert: WT[n][k] = bf16(W[k][n])
//              w = (q-288)/144 in {Wcorr1, Wcorr2, Wsh_bot, Woh_bot}
__global__ __launch_bounds__(256) void prep_kernel(
        const float* __restrict__ embed, const float* __restrict__ mask,
        const float* __restrict__ rel_emb, const int* __restrict__ trel,
        const float* __restrict__ W_corr,
        const float* __restrict__ W_sh, const float* __restrict__ b_sh,
        const float* __restrict__ W_oh, const float* __restrict__ b_oh,
        const float* __restrict__ b_st, const float* __restrict__ b_ot,
        float* __restrict__ pool, float* __restrict__ biasrel,
        unsigned short* __restrict__ embedB, unsigned short* __restrict__ WT,
        float* __restrict__ out_subj, float* __restrict__ out_obj) {
    const int q = blockIdx.x, tid = threadIdx.x;

    if (q < 96) {
        // ---- pool
        const int b = q / 12, c = q % 12;
        __shared__ float mrow[LD];
        __shared__ float msum;
        __shared__ float part[4][64];
        if (tid < LD) mrow[tid] = mask[b * LD + tid];
        __syncthreads();
        if (tid == 0) {
            float s = 0.f;
            for (int l = 0; l < LD; ++l) s += mrow[l];
            msum = s;
        }
        __syncthreads();
        const int lc = tid >> 6, hh = tid & 63;
        const int h = c * 64 + hh;
        float acc = 0.f;
        const float* base = embed + ((size_t)b * LD + lc * 32) * HD + h;
#pragma unroll 8
        for (int i = 0; i < 32; ++i) acc += base[(size_t)i * HD] * mrow[lc * 32 + i];
        part[lc][hh] = acc;
        __syncthreads();
        if (lc == 0)
            pool[b * HD + h] = (part[0][hh] + part[1][hh] + part[2][hh] + part[3][hh]) / msum;
    } else if (q < 192) {
        // ---- biasrel
        const int qq = q - 96;
        const int b = qq / 12, cc = qq % 12;
        __shared__ float re[HD];
        __shared__ float part2[2][128];
        const int rel = trel[b];
        for (int k = tid; k < HD; k += 256) re[k] = rel_emb[(size_t)rel * HD + k];
        if (qq == 0 && tid < 3 * LD) {
            const int l = tid / 3, t = tid - 3 * l;
            out_subj[(l) * 3 + t] = b_st[t];   // b==0 here
            out_obj [(l) * 3 + t] = b_ot[t];
        }
        if (cc == 0 && b > 0 && tid < 3 * LD) {
            const int l = tid / 3, t = tid - 3 * l;
            out_subj[(b * LD + l) * 3 + t] = b_st[t];
            out_obj [(b * LD + l) * 3 + t] = b_ot[t];
        }
        __syncthreads();
        const int kc = tid >> 7, nn = tid & 127;
        const int n = cc * 128 + nn;
        const float* Wp; float bb; int col;
        if (n < HD) { Wp = W_sh; bb = b_sh[n];      col = n; }
        else        { Wp = W_oh; bb = b_oh[n - HD]; col = n - HD; }
        float acc = 0.f;
#pragma unroll 8
        for (int i = 0; i < 384; ++i) {
            const int k = kc * 384 + i;
            acc += re[k] * Wp[(size_t)k * HD + col];
        }
        part2[kc][nn] = acc;
        __syncthreads();
        if (kc == 0) biasrel[b * NF + n] = part2[0][nn] + part2[1][nn] + bb;
    } else if (q < 288) {
        // ---- embed convert (row-major): 8192 elems per block
        const int base = (q - 192) * 8192;
#pragma unroll
        for (int it = 0; it < 4; ++it) {
            const int off = base + it * 2048 + tid * 8;
            float4 v0 = *(const float4*)&embed[off];
            float4 v1 = *(const float4*)&embed[off + 4];
            bf16x8 p;
            p[0] = f2bf(v0.x); p[1] = f2bf(v0.y); p[2] = f2bf(v0.z); p[3] = f2bf(v0.w);
            p[4] = f2bf(v1.x); p[5] = f2bf(v1.y); p[6] = f2bf(v1.z); p[7] = f2bf(v1.w);
            *(bf16x8*)&embedB[off] = p;
        }
    } else {
        // ---- W transpose+convert, one 64x64 tile per block
        const int qq = q - 288;
        const int w = qq / 144, t = qq % 144;
        const int kt = t / 12, nt = t % 12;
        const float* src = (w == 0) ? W_corr
                         : (w == 1) ? W_corr + WSZ
                         : (w == 2) ? W_sh + WSZ
                                    : W_oh + WSZ;
        unsigned short* dst = WT + (size_t)w * WSZ;
        __shared__ float tile[64 * 65];
        const int r = tid >> 2, c4 = (tid & 3) * 16;
#pragma unroll
        for (int i = 0; i < 4; ++i) {
            float4 v = *(const float4*)&src[(size_t)(kt * 64 + r) * HD + nt * 64 + c4 + i * 4];
            tile[r * 65 + c4 + i * 4 + 0] = v.x;
            tile[r * 65 + c4 + i * 4 + 1] = v.y;
            tile[r * 65 + c4 + i * 4 + 2] = v.z;
            tile[r * 65 + c4 + i * 4 + 3] = v.w;
        }
        __syncthreads();
        bf16x8 p0, p1;
#pragma unroll
        for (int j = 0; j < 8; ++j) {
            p0[j] = f2bf(tile[(c4 + j) * 65 + r]);
            p1[j] = f2bf(tile[(c4 + 8 + j) * 65 + r]);
        }
        unsigned short* o = dst + (size_t)(nt * 64 + r) * HD + kt * 64 + c4;
        *(bf16x8*)(o)     = p0;
        *(bf16x8*)(o + 8) = p1;
    }
}

// ---------------------------------------------------------------------------
// Launch 2: biggemm. grid (27, 16), 256 threads.
//  x < 24: dual MFMA GEMM (pre-converted bf16 inputs, shared embed A-tile):
//    GEMM0: AC = embed @ [Wcorr1 | Wcorr2]
//    GEMM1: relu(embed @ [Wsh_bot | Woh_bot] + biasrel) row-dot W_st/W_ot
//           -> atomicAdd into subj/obj
//  x >= 24: relh blocks (48): rh[b,n] = relu(pool@W_hr + b_hr)
__global__ __launch_bounds__(256) void biggemm(
        const unsigned short* __restrict__ embedB,
        const unsigned short* __restrict__ WT,
        const float* __restrict__ biasrel,
        const float* __restrict__ W_st, const float* __restrict__ W_ot,
        const float* __restrict__ pool,
        const float* __restrict__ W_hr, const float* __restrict__ b_hr,
        float* __restrict__ AC, float* __restrict__ out_subj,
        float* __restrict__ out_obj, float* __restrict__ rh) {
    const int tid = threadIdx.x;

    if (blockIdx.x >= 24) {
        const int b = blockIdx.y >> 1;
        const int c = (blockIdx.x - 24) * 2 + (blockIdx.y & 1);
        __shared__ float prow[HD];
        __shared__ float rpart[4][64];
        for (int k = tid; k < HD; k += 256) prow[k] = pool[b * HD + k];
        __syncthreads();
        const int kc = tid >> 6, nn = tid & 63;
        const int n = c * 64 + nn;
        float acc = 0.f;
#pragma unroll 8
        for (int i = 0; i < 192; ++i) {
            const int k = kc * 192 + i;
            acc += prow[k] * W_hr[(size_t)k * H2D + n];
        }
        rpart[kc][nn] = acc;
        __syncthreads();
        if (kc == 0)
            rh[b * H2D + n] = fmaxf(rpart[0][nn] + rpart[1][nn] + rpart[2][nn] + rpart[3][nn] + b_hr[n], 0.f);
        return;
    }

    __shared__ __align__(16) short As [64][40];
    __shared__ __align__(16) short Bs0[64][40];
    __shared__ __align__(16) short Bs1[64][40];
    __shared__ float partial[64][3];

    const int bn0 = blockIdx.x * 64;
    const int bm0 = blockIdx.y * 64;

    const unsigned short* W0 = (bn0 < HD) ? WT : WT + WSZ;                   // corr
    const unsigned short* W1 = (bn0 < HD) ? WT + 2 * (size_t)WSZ : WT + 3 * (size_t)WSZ; // heads
    const int col0 = (bn0 < HD) ? bn0 : bn0 - HD;

    if (tid < 192) partial[tid / 3][tid % 3] = 0.f;

    // staging: row = tid>>2 (0..63), kc8 = (tid&3)*8
    const int row = tid >> 2;
    const int kc8 = (tid & 3) * 8;

    // compute indices
    const int lane = tid & 63;
    const int wv = tid >> 6;
    const int wm = (wv >> 1) * 32;
    const int wn = (wv & 1) * 32;
    const int fr = lane & 15;
    const int kq = (lane >> 4) * 8;
    const int mq = (lane >> 4) * 4;

    f32x4 c00 = {0.f,0.f,0.f,0.f}, c01 = c00, c10 = c00, c11 = c00;
    f32x4 h00 = c00, h01 = c00, h10 = c00, h11 = c00;

    for (int kt = 0; kt < 24; ++kt) {
        const int k0 = kt << 5;
        bf16x8 av = *(const bf16x8*)&embedB[(size_t)(bm0 + row) * HD + k0 + kc8];
        bf16x8 b0v = *(const bf16x8*)&W0[(size_t)(col0 + row) * HD + k0 + kc8];
        bf16x8 b1v = *(const bf16x8*)&W1[(size_t)(col0 + row) * HD + k0 + kc8];

        __syncthreads();
        *(bf16x8*)&As [row][kc8] = av;
        *(bf16x8*)&Bs0[row][kc8] = b0v;
        *(bf16x8*)&Bs1[row][kc8] = b1v;
        __syncthreads();

        bf16x8 a0 = *(bf16x8*)&As[wm + fr][kq];
        bf16x8 a1 = *(bf16x8*)&As[wm + 16 + fr][kq];
        bf16x8 b0 = *(bf16x8*)&Bs0[wn + fr][kq];
        bf16x8 b1 = *(bf16x8*)&Bs0[wn + 16 + fr][kq];
        bf16x8 d0 = *(bf16x8*)&Bs1[wn + fr][kq];
        bf16x8 d1 = *(bf16x8*)&Bs1[wn + 16 + fr][kq];
        c00 = __builtin_amdgcn_mfma_f32_16x16x32_bf16(a0, b0, c00, 0, 0, 0);
        c01 = __builtin_amdgcn_mfma_f32_16x16x32_bf16(a0, b1, c01, 0, 0, 0);
        c10 = __builtin_amdgcn_mfma_f32_16x16x32_bf16(a1, b0, c10, 0, 0, 0);
        c11 = __builtin_amdgcn_mfma_f32_16x16x32_bf16(a1, b1, c11, 0, 0, 0);
        h00 = __builtin_amdgcn_mfma_f32_16x16x32_bf16(a0, d0, h00, 0, 0, 0);
        h01 = __builtin_amdgcn_mfma_f32_16x16x32_bf16(a0, d1, h01, 0, 0, 0);
        h10 = __builtin_amdgcn_mfma_f32_16x16x32_bf16(a1, d0, h10, 0, 0, 0);
        h11 = __builtin_amdgcn_mfma_f32_16x16x32_bf16(a1, d1, h11, 0, 0, 0);
    }

    // ---- GEMM0 epilogue: store AC tile. C/D layout col=lane&15, row=quad*4+reg.
#pragma unroll
    for (int i = 0; i < 2; ++i) {
#pragma unroll
        for (int j = 0; j < 2; ++j) {
            f32x4 a = (i == 0) ? (j == 0 ? c00 : c01) : (j == 0 ? c10 : c11);
            const int ncol = bn0 + wn + j * 16 + fr;
#pragma unroll
            for (int r = 0; r < 4; ++r) {
                const int mrow = bm0 + wm + i * 16 + mq + r;
                AC[(size_t)mrow * NF + ncol] = a[r];
            }
        }
    }

    // ---- GEMM1 epilogue
    {
        const float* brl = biasrel + (size_t)(bm0 / LD) * NF;
        const float* Wt = (bn0 < HD) ? W_st : W_ot;
        float* op = (bn0 < HD) ? out_subj : out_obj;
        float pt[8][3] = {};
#pragma unroll
        for (int j = 0; j < 2; ++j) {
            const int ncol = bn0 + wn + j * 16 + fr;
            const int ncl = (bn0 < HD) ? ncol : ncol - HD;
            const float wt0 = Wt[ncl * 3 + 0];
            const float wt1 = Wt[ncl * 3 + 1];
            const float wt2 = Wt[ncl * 3 + 2];
            const float bias = brl[ncol];
#pragma unroll
            for (int i = 0; i < 2; ++i) {
                f32x4 a = (i == 0) ? (j == 0 ? h00 : h01) : (j == 0 ? h10 : h11);
#pragma unroll
                for (int r = 0; r < 4; ++r) {
                    const float v = fmaxf(a[r] + bias, 0.f);
                    pt[i * 4 + r][0] += v * wt0;
                    pt[i * 4 + r][1] += v * wt1;
                    pt[i * 4 + r][2] += v * wt2;
                }
            }
        }
#pragma unroll
        for (int mask = 1; mask < 16; mask <<= 1) {
#pragma unroll
            for (int x = 0; x < 8; ++x)
#pragma unroll
                for (int t = 0; t < 3; ++t)
                    pt[x][t] += __shfl_xor(pt[x][t], mask, 64);
        }
        if (fr == 0) {
#pragma unroll
            for (int i = 0; i < 2; ++i)
#pragma unroll
                for (int r = 0; r < 4; ++r)
#pragma unroll
                    for (int t = 0; t < 3; ++t)
                        atomicAdd(&partial[wm + i * 16 + mq + r][t], pt[i * 4 + r][t]);
        }
        __syncthreads();
        if (tid < 192) {
            const int m = tid / 3, t = tid % 3;
            atomicAdd(&op[(size_t)(bm0 + m) * 3 + t], partial[m][t]);
        }
    }
}

// ---------------------------------------------------------------------------
// Launch 3: corres + stage1. grid (17, 8), 512 threads (8 waves).
//  x < 16: pred_corres[b, i0..i0+8, :] (8 i's per block, packed-f32 inner loop)
//  x == 16: stage1 for batch y
__global__ __launch_bounds__(512) void corres_kernel(
        const float* __restrict__ AC,
        const float* __restrict__ b_corr, const float* __restrict__ W_gc,
        const float* __restrict__ b_gc,
        const float* __restrict__ rh,
        const float* __restrict__ W_rj, const float* __restrict__ b_rj,
        float* __restrict__ out, float* __restrict__ out_stage1) {
    const int b = blockIdx.y;
    const int tid = threadIdx.x;

    if (blockIdx.x == 16) {
        __shared__ float rl[H2D];
        __shared__ float spart[8][RD];
        if (tid < H2D) rl[tid] = rh[b * H2D + tid];
        __syncthreads();
        if (tid < 8 * RD) {
            const int n = tid % RD, kc = tid / RD;
            float acc = 0.f;
#pragma unroll 8
            for (int i = 0; i < 48; ++i) {
                const int k = kc * 48 + i;
                acc += rl[k] * W_rj[k * RD + n];
            }
            spart[kc][n] = acc;
        }
        __syncthreads();
        if (tid < RD) {
            float s = b_rj[tid];
#pragma unroll
            for (int q = 0; q < 8; ++q) s += spart[q][tid];
            out_stage1[b * RD + tid] = s;
        }
        return;
    }

    const int i0 = blockIdx.x * 8;
    const int lane = tid & 63;
    const int wave = tid >> 6;  // 0..7

    f32x4 wg[3], cb[8][3];
#pragma unroll
    for (int s = 0; s < 3; ++s) {
        const int h = s * 256 + lane * 4;
        f32x4 w  = *(const f32x4*)&W_gc[h];
        f32x4 bc = *(const f32x4*)&b_corr[h];
        wg[s] = w;
#pragma unroll
        for (int i = 0; i < 8; ++i) {
            f32x4 cv = *(const f32x4*)&AC[((size_t)(b * LD + i0 + i)) * NF + HD + h];
            cb[i][s] = cv + bc;
        }
    }
    const float bg = b_gc[0];

    // software-pipelined over j (stride 8): prefetch next A row
    f32x4 a[3];
    {
        const float* ar = AC + ((size_t)(b * LD + wave)) * NF;
#pragma unroll
        for (int s = 0; s < 3; ++s) a[s] = *(const f32x4*)&ar[s * 256 + lane * 4];
    }
    for (int j = wave; j < LD; j += 8) {
        f32x4 an[3];
        if (j + 8 < LD) {
            const float* ar = AC + ((size_t)(b * LD + j + 8)) * NF;
#pragma unroll
            for (int s = 0; s < 3; ++s) an[s] = *(const f32x4*)&ar[s * 256 + lane * 4];
        }
        f32x4 sv[8];
#pragma unroll
        for (int i = 0; i < 8; ++i) sv[i] = (f32x4){0.f, 0.f, 0.f, 0.f};
#pragma unroll
        for (int s = 0; s < 3; ++s) {
#pragma unroll
            for (int i = 0; i < 8; ++i)
                sv[i] += vmax0(a[s] + cb[i][s]) * wg[s];   // v_pk_* packed f32
        }
#pragma unroll
        for (int i = 0; i < 8; ++i) {
            float r = (sv[i][0] + sv[i][1]) + (sv[i][2] + sv[i][3]);
#pragma unroll
            for (int off = 32; off > 0; off >>= 1) r += __shfl_down(r, off, 64);
            if (lane == 0)
                out[((size_t)(b * LD + i0 + i)) * LD + j] = r + bg;
        }
#pragma unroll
        for (int s = 0; s < 3; ++s) a[s] = an[s];
    }
}

// ---------------------------------------------------------------------------
extern "C" void kernel_launch(void* const* d_in, const int* in_sizes, int n_in,
                              void* d_out, int out_size, void* d_ws, size_t ws_size,
                              hipStream_t stream) {
    const float* embed   = (const float*)d_in[0];
    const float* mask    = (const float*)d_in[1];
    const int*   trel    = (const int*)d_in[2];
    const float* W_hr    = (const float*)d_in[3];
    const float* b_hr    = (const float*)d_in[4];
    const float* W_rj    = (const float*)d_in[5];
    const float* b_rj    = (const float*)d_in[6];
    const float* rel_emb = (const float*)d_in[7];
    const float* W_corr  = (const float*)d_in[8];
    const float* b_corr  = (const float*)d_in[9];
    const float* W_gc    = (const float*)d_in[10];
    const float* b_gc    = (const float*)d_in[11];
    const float* W_sh    = (const float*)d_in[12];
    const float* b_sh    = (const float*)d_in[13];
    const float* W_st    = (const float*)d_in[14];
    const float* b_st    = (const float*)d_in[15];
    const float* W_oh    = (const float*)d_in[16];
    const float* b_oh    = (const float*)d_in[17];
    const float* W_ot    = (const float*)d_in[18];
    const float* b_ot    = (const float*)d_in[19];
    float* out = (float*)d_out;

    float* ws      = (float*)d_ws;
    float* AC      = ws;                             // 1,572,864 floats
    float* biasrel = ws + 1572864;                   // 12,288
    float* rh      = ws + 1572864 + 12288;           // 3,072
    float* pool    = ws + 1572864 + 12288 + 3072;    // 6,144
    unsigned short* embedB = (unsigned short*)(ws + 1594368);          // 786,432 shorts
    unsigned short* WT     = (unsigned short*)(ws + 1594368 + 393216); // 4*589,824 shorts

    // Output layout: stage1[192] | subj[3072] | obj[3072] | pred_corres[131072]
    float* out_stage1 = out;
    float* out_subj   = out + 192;
    float* out_obj    = out + 3264;
    float* out_corr   = out + 6336;

    prep_kernel<<<864, 256, 0, stream>>>(embed, mask, rel_emb, trel, W_corr,
                                         W_sh, b_sh, W_oh, b_oh, b_st, b_ot,
                                         pool, biasrel, embedB, WT,
                                         out_subj, out_obj);

    biggemm<<<dim3(27, 16), 256, 0, stream>>>(embedB, WT, biasrel, W_st, W_ot,
                                              pool, W_hr, b_hr,
                                              AC, out_subj, out_obj, rh);

    corres_kernel<<<dim3(17, BD), 512, 0, stream>>>(AC, b_corr, W_gc, b_gc,
                                                    rh, W_rj, b_rj, out_corr, out_stage1);
}

// Round 11
// 165.859 us; speedup vs baseline: 1.9127x; 1.1018x over previous
//
#include <hip/hip_runtime.h>
#include <hip/hip_bf16.h>

// Problem dims (fixed): B=8, L=128, H=768, R=24
#define BD   8
#define LD   128
#define HD   768
#define RD   24
#define H2D  384
#define NF   1536   // fused N (two heads side by side)
#define WSZ  589824 // 768*768

typedef __attribute__((ext_vector_type(8))) short bf16x8;
typedef __attribute__((ext_vector_type(4))) float f32x4;

__device__ __forceinline__ short f2bf(float f) {
    __hip_bfloat16 h = __float2bfloat16(f);
    return *reinterpret_cast<short*>(&h);
}

__device__ __forceinline__ f32x4 vmax0(f32x4 v) {
    f32x4 r;
    r[0] = fmaxf(v[0], 0.f); r[1] = fmaxf(v[1], 0.f);
    r[2] = fmaxf(v[2], 0.f); r[3] = fmaxf(v[3], 0.f);
    return r;
}

// ---------------------------------------------------------------------------
// Launch 1: prep. 864 blocks x 256 threads, flat blockIdx.x:
//   [0,96):    pool       (b = q/12, c = q%12; 4-way split over L)
//   [96,192):  biasrel    = re@Wtop + bias (2-way split-K); q==96 inits subj/obj
//   [192,288): embed fp32 -> bf16 (row-major, no transpose)
//   [288,864): W 64x64 tile transpose+convert: WT[n][k] = bf16(W[k][n])
__global__ __launch_bounds__(256) void prep_kernel(
        const float* __restrict__ embed, const float* __restrict__ mask,
        const float* __restrict__ rel_emb, const int* __restrict__ trel,
        const float* __restrict__ W_corr,
        const float* __restrict__ W_sh, const float* __restrict__ b_sh,
        const float* __restrict__ W_oh, const float* __restrict__ b_oh,
        const float* __restrict__ b_st, const float* __restrict__ b_ot,
        float* __restrict__ pool, float* __restrict__ biasrel,
        unsigned short* __restrict__ embedB, unsigned short* __restrict__ WT,
        float* __restrict__ out_subj, float* __restrict__ out_obj) {
    const int q = blockIdx.x, tid = threadIdx.x;

    if (q < 96) {
        const int b = q / 12, c = q % 12;
        __shared__ float mrow[LD];
        __shared__ float msum;
        __shared__ float part[4][64];
        if (tid < LD) mrow[tid] = mask[b * LD + tid];
        __syncthreads();
        if (tid == 0) {
            float s = 0.f;
            for (int l = 0; l < LD; ++l) s += mrow[l];
            msum = s;
        }
        __syncthreads();
        const int lc = tid >> 6, hh = tid & 63;
        const int h = c * 64 + hh;
        float acc = 0.f;
        const float* base = embed + ((size_t)b * LD + lc * 32) * HD + h;
#pragma unroll 8
        for (int i = 0; i < 32; ++i) acc += base[(size_t)i * HD] * mrow[lc * 32 + i];
        part[lc][hh] = acc;
        __syncthreads();
        if (lc == 0)
            pool[b * HD + h] = (part[0][hh] + part[1][hh] + part[2][hh] + part[3][hh]) / msum;
    } else if (q < 192) {
        const int qq = q - 96;
        const int b = qq / 12, cc = qq % 12;
        __shared__ float re[HD];
        __shared__ float part2[2][128];
        const int rel = trel[b];
        for (int k = tid; k < HD; k += 256) re[k] = rel_emb[(size_t)rel * HD + k];
        if (cc == 0 && tid < 3 * LD) {
            const int l = tid / 3, t = tid - 3 * l;
            out_subj[(b * LD + l) * 3 + t] = b_st[t];
            out_obj [(b * LD + l) * 3 + t] = b_ot[t];
        }
        __syncthreads();
        const int kc = tid >> 7, nn = tid & 127;
        const int n = cc * 128 + nn;
        const float* Wp; float bb; int col;
        if (n < HD) { Wp = W_sh; bb = b_sh[n];      col = n; }
        else        { Wp = W_oh; bb = b_oh[n - HD]; col = n - HD; }
        float acc = 0.f;
#pragma unroll 8
        for (int i = 0; i < 384; ++i) {
            const int k = kc * 384 + i;
            acc += re[k] * Wp[(size_t)k * HD + col];
        }
        part2[kc][nn] = acc;
        __syncthreads();
        if (kc == 0) biasrel[b * NF + n] = part2[0][nn] + part2[1][nn] + bb;
    } else if (q < 288) {
        const int base = (q - 192) * 8192;
#pragma unroll
        for (int it = 0; it < 4; ++it) {
            const int off = base + it * 2048 + tid * 8;
            float4 v0 = *(const float4*)&embed[off];
            float4 v1 = *(const float4*)&embed[off + 4];
            bf16x8 p;
            p[0] = f2bf(v0.x); p[1] = f2bf(v0.y); p[2] = f2bf(v0.z); p[3] = f2bf(v0.w);
            p[4] = f2bf(v1.x); p[5] = f2bf(v1.y); p[6] = f2bf(v1.z); p[7] = f2bf(v1.w);
            *(bf16x8*)&embedB[off] = p;
        }
    } else {
        const int qq = q - 288;
        const int w = qq / 144, t = qq % 144;
        const int kt = t / 12, nt = t % 12;
        const float* src = (w == 0) ? W_corr
                         : (w == 1) ? W_corr + WSZ
                         : (w == 2) ? W_sh + WSZ
                                    : W_oh + WSZ;
        unsigned short* dst = WT + (size_t)w * WSZ;
        __shared__ float tile[64 * 65];
        const int r = tid >> 2, c4 = (tid & 3) * 16;
#pragma unroll
        for (int i = 0; i < 4; ++i) {
            float4 v = *(const float4*)&src[(size_t)(kt * 64 + r) * HD + nt * 64 + c4 + i * 4];
            tile[r * 65 + c4 + i * 4 + 0] = v.x;
            tile[r * 65 + c4 + i * 4 + 1] = v.y;
            tile[r * 65 + c4 + i * 4 + 2] = v.z;
            tile[r * 65 + c4 + i * 4 + 3] = v.w;
        }
        __syncthreads();
        bf16x8 p0, p1;
#pragma unroll
        for (int j = 0; j < 8; ++j) {
            p0[j] = f2bf(tile[(c4 + j) * 65 + r]);
            p1[j] = f2bf(tile[(c4 + 8 + j) * 65 + r]);
        }
        unsigned short* o = dst + (size_t)(nt * 64 + r) * HD + kt * 64 + c4;
        *(bf16x8*)(o)     = p0;
        *(bf16x8*)(o + 8) = p1;
    }
}

// ---------------------------------------------------------------------------
// Launch 2: biggemm. grid (27, 16), 256 threads. (unchanged from round 7)
__global__ __launch_bounds__(256) void biggemm(
        const unsigned short* __restrict__ embedB,
        const unsigned short* __restrict__ WT,
        const float* __restrict__ biasrel,
        const float* __restrict__ W_st, const float* __restrict__ W_ot,
        const float* __restrict__ pool,
        const float* __restrict__ W_hr, const float* __restrict__ b_hr,
        float* __restrict__ AC, float* __restrict__ out_subj,
        float* __restrict__ out_obj, float* __restrict__ rh) {
    const int tid = threadIdx.x;

    if (blockIdx.x >= 24) {
        const int b = blockIdx.y >> 1;
        const int c = (blockIdx.x - 24) * 2 + (blockIdx.y & 1);
        __shared__ float prow[HD];
        __shared__ float rpart[4][64];
        for (int k = tid; k < HD; k += 256) prow[k] = pool[b * HD + k];
        __syncthreads();
        const int kc = tid >> 6, nn = tid & 63;
        const int n = c * 64 + nn;
        float acc = 0.f;
#pragma unroll 8
        for (int i = 0; i < 192; ++i) {
            const int k = kc * 192 + i;
            acc += prow[k] * W_hr[(size_t)k * H2D + n];
        }
        rpart[kc][nn] = acc;
        __syncthreads();
        if (kc == 0)
            rh[b * H2D + n] = fmaxf(rpart[0][nn] + rpart[1][nn] + rpart[2][nn] + rpart[3][nn] + b_hr[n], 0.f);
        return;
    }

    __shared__ __align__(16) short As [64][40];
    __shared__ __align__(16) short Bs0[64][40];
    __shared__ __align__(16) short Bs1[64][40];
    __shared__ float partial[64][3];

    const int bn0 = blockIdx.x * 64;
    const int bm0 = blockIdx.y * 64;

    const unsigned short* W0 = (bn0 < HD) ? WT : WT + WSZ;
    const unsigned short* W1 = (bn0 < HD) ? WT + 2 * (size_t)WSZ : WT + 3 * (size_t)WSZ;
    const int col0 = (bn0 < HD) ? bn0 : bn0 - HD;

    if (tid < 192) partial[tid / 3][tid % 3] = 0.f;

    const int row = tid >> 2;
    const int kc8 = (tid & 3) * 8;
    const int lane = tid & 63;
    const int wv = tid >> 6;
    const int wm = (wv >> 1) * 32;
    const int wn = (wv & 1) * 32;
    const int fr = lane & 15;
    const int kq = (lane >> 4) * 8;
    const int mq = (lane >> 4) * 4;

    f32x4 c00 = {0.f,0.f,0.f,0.f}, c01 = c00, c10 = c00, c11 = c00;
    f32x4 h00 = c00, h01 = c00, h10 = c00, h11 = c00;

    for (int kt = 0; kt < 24; ++kt) {
        const int k0 = kt << 5;
        bf16x8 av = *(const bf16x8*)&embedB[(size_t)(bm0 + row) * HD + k0 + kc8];
        bf16x8 b0v = *(const bf16x8*)&W0[(size_t)(col0 + row) * HD + k0 + kc8];
        bf16x8 b1v = *(const bf16x8*)&W1[(size_t)(col0 + row) * HD + k0 + kc8];

        __syncthreads();
        *(bf16x8*)&As [row][kc8] = av;
        *(bf16x8*)&Bs0[row][kc8] = b0v;
        *(bf16x8*)&Bs1[row][kc8] = b1v;
        __syncthreads();

        bf16x8 a0 = *(bf16x8*)&As[wm + fr][kq];
        bf16x8 a1 = *(bf16x8*)&As[wm + 16 + fr][kq];
        bf16x8 b0 = *(bf16x8*)&Bs0[wn + fr][kq];
        bf16x8 b1 = *(bf16x8*)&Bs0[wn + 16 + fr][kq];
        bf16x8 d0 = *(bf16x8*)&Bs1[wn + fr][kq];
        bf16x8 d1 = *(bf16x8*)&Bs1[wn + 16 + fr][kq];
        c00 = __builtin_amdgcn_mfma_f32_16x16x32_bf16(a0, b0, c00, 0, 0, 0);
        c01 = __builtin_amdgcn_mfma_f32_16x16x32_bf16(a0, b1, c01, 0, 0, 0);
        c10 = __builtin_amdgcn_mfma_f32_16x16x32_bf16(a1, b0, c10, 0, 0, 0);
        c11 = __builtin_amdgcn_mfma_f32_16x16x32_bf16(a1, b1, c11, 0, 0, 0);
        h00 = __builtin_amdgcn_mfma_f32_16x16x32_bf16(a0, d0, h00, 0, 0, 0);
        h01 = __builtin_amdgcn_mfma_f32_16x16x32_bf16(a0, d1, h01, 0, 0, 0);
        h10 = __builtin_amdgcn_mfma_f32_16x16x32_bf16(a1, d0, h10, 0, 0, 0);
        h11 = __builtin_amdgcn_mfma_f32_16x16x32_bf16(a1, d1, h11, 0, 0, 0);
    }

#pragma unroll
    for (int i = 0; i < 2; ++i) {
#pragma unroll
        for (int j = 0; j < 2; ++j) {
            f32x4 a = (i == 0) ? (j == 0 ? c00 : c01) : (j == 0 ? c10 : c11);
            const int ncol = bn0 + wn + j * 16 + fr;
#pragma unroll
            for (int r = 0; r < 4; ++r) {
                const int mrow = bm0 + wm + i * 16 + mq + r;
                AC[(size_t)mrow * NF + ncol] = a[r];
            }
        }
    }

    {
        const float* brl = biasrel + (size_t)(bm0 / LD) * NF;
        const float* Wt = (bn0 < HD) ? W_st : W_ot;
        float* op = (bn0 < HD) ? out_subj : out_obj;
        float pt[8][3] = {};
#pragma unroll
        for (int j = 0; j < 2; ++j) {
            const int ncol = bn0 + wn + j * 16 + fr;
            const int ncl = (bn0 < HD) ? ncol : ncol - HD;
            const float wt0 = Wt[ncl * 3 + 0];
            const float wt1 = Wt[ncl * 3 + 1];
            const float wt2 = Wt[ncl * 3 + 2];
            const float bias = brl[ncol];
#pragma unroll
            for (int i = 0; i < 2; ++i) {
                f32x4 a = (i == 0) ? (j == 0 ? h00 : h01) : (j == 0 ? h10 : h11);
#pragma unroll
                for (int r = 0; r < 4; ++r) {
                    const float v = fmaxf(a[r] + bias, 0.f);
                    pt[i * 4 + r][0] += v * wt0;
                    pt[i * 4 + r][1] += v * wt1;
                    pt[i * 4 + r][2] += v * wt2;
                }
            }
        }
#pragma unroll
        for (int mask = 1; mask < 16; mask <<= 1) {
#pragma unroll
            for (int x = 0; x < 8; ++x)
#pragma unroll
                for (int t = 0; t < 3; ++t)
                    pt[x][t] += __shfl_xor(pt[x][t], mask, 64);
        }
        if (fr == 0) {
#pragma unroll
            for (int i = 0; i < 2; ++i)
#pragma unroll
                for (int r = 0; r < 4; ++r)
#pragma unroll
                    for (int t = 0; t < 3; ++t)
                        atomicAdd(&partial[wm + i * 16 + mq + r][t], pt[i * 4 + r][t]);
        }
        __syncthreads();
        if (tid < 192) {
            const int m = tid / 3, t = tid % 3;
            atomicAdd(&op[(size_t)(bm0 + m) * 3 + t], partial[m][t]);
        }
    }
}

// ---------------------------------------------------------------------------
// Launch 3: corres + stage1. grid (33, 8), 512 threads (8 waves).
//  x < 32: pred_corres[b, i0..i0+4, :] — packed-f32 inner + j+8 prefetch
//  x == 32: stage1 for batch y
__global__ __launch_bounds__(512) void corres_kernel(
        const float* __restrict__ AC,
        const float* __restrict__ b_corr, const float* __restrict__ W_gc,
        const float* __restrict__ b_gc,
        const float* __restrict__ rh,
        const float* __restrict__ W_rj, const float* __restrict__ b_rj,
        float* __restrict__ out, float* __restrict__ out_stage1) {
    const int b = blockIdx.y;
    const int tid = threadIdx.x;

    if (blockIdx.x == 32) {
        __shared__ float rl[H2D];
        __shared__ float spart[8][RD];
        if (tid < H2D) rl[tid] = rh[b * H2D + tid];
        __syncthreads();
        if (tid < 8 * RD) {
            const int n = tid % RD, kc = tid / RD;
            float acc = 0.f;
#pragma unroll 8
            for (int i = 0; i < 48; ++i) {
                const int k = kc * 48 + i;
                acc += rl[k] * W_rj[k * RD + n];
            }
            spart[kc][n] = acc;
        }
        __syncthreads();
        if (tid < RD) {
            float s = b_rj[tid];
#pragma unroll
            for (int q = 0; q < 8; ++q) s += spart[q][tid];
            out_stage1[b * RD + tid] = s;
        }
        return;
    }

    const int i0 = blockIdx.x * 4;
    const int lane = tid & 63;
    const int wave = tid >> 6;  // 0..7

    f32x4 wg[3], cb[4][3];
#pragma unroll
    for (int s = 0; s < 3; ++s) {
        const int h = s * 256 + lane * 4;
        f32x4 w  = *(const f32x4*)&W_gc[h];
        f32x4 bc = *(const f32x4*)&b_corr[h];
        wg[s] = w;
#pragma unroll
        for (int i = 0; i < 4; ++i) {
            f32x4 cv = *(const f32x4*)&AC[((size_t)(b * LD + i0 + i)) * NF + HD + h];
            cb[i][s] = cv + bc;
        }
    }
    const float bg = b_gc[0];

    // j-loop stride 8 with one-deep prefetch
    f32x4 a[3];
    {
        const float* ar = AC + ((size_t)(b * LD + wave)) * NF;
#pragma unroll
        for (int s = 0; s < 3; ++s) a[s] = *(const f32x4*)&ar[s * 256 + lane * 4];
    }
    for (int j = wave; j < LD; j += 8) {
        f32x4 an[3];
        if (j + 8 < LD) {
            const float* ar = AC + ((size_t)(b * LD + j + 8)) * NF;
#pragma unroll
            for (int s = 0; s < 3; ++s) an[s] = *(const f32x4*)&ar[s * 256 + lane * 4];
        }
        f32x4 sv[4];
#pragma unroll
        for (int i = 0; i < 4; ++i) sv[i] = (f32x4){0.f, 0.f, 0.f, 0.f};
#pragma unroll
        for (int s = 0; s < 3; ++s) {
#pragma unroll
            for (int i = 0; i < 4; ++i)
                sv[i] += vmax0(a[s] + cb[i][s]) * wg[s];   // packed v_pk_* f32
        }
#pragma unroll
        for (int i = 0; i < 4; ++i) {
            float r = (sv[i][0] + sv[i][1]) + (sv[i][2] + sv[i][3]);
#pragma unroll
            for (int off = 32; off > 0; off >>= 1) r += __shfl_down(r, off, 64);
            if (lane == 0)
                out[((size_t)(b * LD + i0 + i)) * LD + j] = r + bg;
        }
#pragma unroll
        for (int s = 0; s < 3; ++s) a[s] = an[s];
    }
}

// ---------------------------------------------------------------------------
extern "C" void kernel_launch(void* const* d_in, const int* in_sizes, int n_in,
                              void* d_out, int out_size, void* d_ws, size_t ws_size,
                              hipStream_t stream) {
    const float* embed   = (const float*)d_in[0];
    const float* mask    = (const float*)d_in[1];
    const int*   trel    = (const int*)d_in[2];
    const float* W_hr    = (const float*)d_in[3];
    const float* b_hr    = (const float*)d_in[4];
    const float* W_rj    = (const float*)d_in[5];
    const float* b_rj    = (const float*)d_in[6];
    const float* rel_emb = (const float*)d_in[7];
    const float* W_corr  = (const float*)d_in[8];
    const float* b_corr  = (const float*)d_in[9];
    const float* W_gc    = (const float*)d_in[10];
    const float* b_gc    = (const float*)d_in[11];
    const float* W_sh    = (const float*)d_in[12];
    const float* b_sh    = (const float*)d_in[13];
    const float* W_st    = (const float*)d_in[14];
    const float* b_st    = (const float*)d_in[15];
    const float* W_oh    = (const float*)d_in[16];
    const float* b_oh    = (const float*)d_in[17];
    const float* W_ot    = (const float*)d_in[18];
    const float* b_ot    = (const float*)d_in[19];
    float* out = (float*)d_out;

    float* ws      = (float*)d_ws;
    float* AC      = ws;                             // 1,572,864 floats
    float* biasrel = ws + 1572864;                   // 12,288
    float* rh      = ws + 1572864 + 12288;           // 3,072
    float* pool    = ws + 1572864 + 12288 + 3072;    // 6,144
    unsigned short* embedB = (unsigned short*)(ws + 1594368);          // 786,432 shorts
    unsigned short* WT     = (unsigned short*)(ws + 1594368 + 393216); // 4*589,824 shorts

    // Output layout: stage1[192] | subj[3072] | obj[3072] | pred_corres[131072]
    float* out_stage1 = out;
    float* out_subj   = out + 192;
    float* out_obj    = out + 3264;
    float* out_corr   = out + 6336;

    prep_kernel<<<864, 256, 0, stream>>>(embed, mask, rel_emb, trel, W_corr,
                                         W_sh, b_sh, W_oh, b_oh, b_st, b_ot,
                                         pool, biasrel, embedB, WT,
                                         out_subj, out_obj);

    biggemm<<<dim3(27, 16), 256, 0, stream>>>(embedB, WT, biasrel, W_st, W_ot,
                                              pool, W_hr, b_hr,
                                              AC, out_subj, out_obj, rh);

    corres_kernel<<<dim3(33, BD), 512, 0, stream>>>(AC, b_corr, W_gc, b_gc,
                                                    rh, W_rj, b_rj, out_corr, out_stage1);
}

// Round 12
// 160.894 us; speedup vs baseline: 1.9717x; 1.0309x over previous
//
#include <hip/hip_runtime.h>
#include <hip/hip_bf16.h>

// Problem dims (fixed): B=8, L=128, H=768, R=24
#define BD   8
#define LD   128
#define HD   768
#define RD   24
#define H2D  384
#define NF   1536   // fused N (two heads side by side)
#define WSZ  589824 // 768*768

typedef __attribute__((ext_vector_type(8))) short bf16x8;
typedef __attribute__((ext_vector_type(4))) float f32x4;

__device__ __forceinline__ short f2bf(float f) {
    __hip_bfloat16 h = __float2bfloat16(f);
    return *reinterpret_cast<short*>(&h);
}

__device__ __forceinline__ f32x4 vmax0(f32x4 v) {
    f32x4 r;
    r[0] = fmaxf(v[0], 0.f); r[1] = fmaxf(v[1], 0.f);
    r[2] = fmaxf(v[2], 0.f); r[3] = fmaxf(v[3], 0.f);
    return r;
}

// ---------------------------------------------------------------------------
// Launch 1: prep. 792 blocks x 256 threads, flat blockIdx.x:
//   [0,96):    pool     (b = q/12, c = q%12; 4-way split over L)
//   [96,120):  biasrel  24 blocks; each reads its 64 weight cols ONCE and
//              applies to all 8 batches' re vectors (8x less weight traffic).
//              q==96 also bias-inits subj/obj.
//   [120,216): embed fp32 -> bf16 (row-major)
//   [216,792): W 64x64 tile transpose+convert: WT[n][k] = bf16(W[k][n])
__global__ __launch_bounds__(256) void prep_kernel(
        const float* __restrict__ embed, const float* __restrict__ mask,
        const float* __restrict__ rel_emb, const int* __restrict__ trel,
        const float* __restrict__ W_corr,
        const float* __restrict__ W_sh, const float* __restrict__ b_sh,
        const float* __restrict__ W_oh, const float* __restrict__ b_oh,
        const float* __restrict__ b_st, const float* __restrict__ b_ot,
        float* __restrict__ pool, float* __restrict__ biasrel,
        unsigned short* __restrict__ embedB, unsigned short* __restrict__ WT,
        float* __restrict__ out_subj, float* __restrict__ out_obj) {
    const int q = blockIdx.x, tid = threadIdx.x;

    if (q < 96) {
        // ---- pool
        const int b = q / 12, c = q % 12;
        __shared__ float mrow[LD];
        __shared__ float msum;
        __shared__ float part[4][64];
        if (tid < LD) mrow[tid] = mask[b * LD + tid];
        __syncthreads();
        if (tid == 0) {
            float s = 0.f;
            for (int l = 0; l < LD; ++l) s += mrow[l];
            msum = s;
        }
        __syncthreads();
        const int lc = tid >> 6, hh = tid & 63;
        const int h = c * 64 + hh;
        float acc = 0.f;
        const float* base = embed + ((size_t)b * LD + lc * 32) * HD + h;
#pragma unroll 8
        for (int i = 0; i < 32; ++i) acc += base[(size_t)i * HD] * mrow[lc * 32 + i];
        part[lc][hh] = acc;
        __syncthreads();
        if (lc == 0)
            pool[b * HD + h] = (part[0][hh] + part[1][hh] + part[2][hh] + part[3][hh]) / msum;
    } else if (q < 120) {
        // ---- biasrel: block c handles 64 cols for ALL 8 batches
        const int c = q - 96;             // 0..23
        __shared__ float reAll[8][HD];    // 24.6 KB
        __shared__ float part[4][8][64];  // 8 KB
        for (int u = tid; u < 8 * HD; u += 256) {
            const int b = u / HD, k = u - b * HD;
            reAll[b][k] = rel_emb[(size_t)trel[b] * HD + k];
        }
        if (c == 0) {
            for (int u = tid; u < 3 * LD * BD; u += 256) {
                const int b = u / (3 * LD), rem = u - b * (3 * LD);
                const int l = rem / 3, t = rem - 3 * l;
                out_subj[(b * LD + l) * 3 + t] = b_st[t];
                out_obj [(b * LD + l) * 3 + t] = b_ot[t];
            }
        }
        __syncthreads();
        const int kc = tid >> 6, nn = tid & 63;
        const int n = c * 64 + nn;
        const float* Wp; int col;
        if (n < HD) { Wp = W_sh; col = n; }
        else        { Wp = W_oh; col = n - HD; }
        float acc[8] = {};
        for (int i = 0; i < 192; ++i) {
            const int k = kc * 192 + i;
            const float w = Wp[(size_t)k * HD + col];
#pragma unroll
            for (int b = 0; b < 8; ++b) acc[b] += reAll[b][k] * w;
        }
#pragma unroll
        for (int b = 0; b < 8; ++b) part[kc][b][nn] = acc[b];
        __syncthreads();
        {
            const float bb = (n < HD) ? b_sh[col] : b_oh[col];
            const int b0 = kc, b1 = kc + 4;
            float s0 = part[0][b0][nn] + part[1][b0][nn] + part[2][b0][nn] + part[3][b0][nn];
            float s1 = part[0][b1][nn] + part[1][b1][nn] + part[2][b1][nn] + part[3][b1][nn];
            biasrel[b0 * NF + n] = s0 + bb;
            biasrel[b1 * NF + n] = s1 + bb;
        }
    } else if (q < 216) {
        // ---- embed convert (row-major): 8192 elems per block
        const int base = (q - 120) * 8192;
#pragma unroll
        for (int it = 0; it < 4; ++it) {
            const int off = base + it * 2048 + tid * 8;
            float4 v0 = *(const float4*)&embed[off];
            float4 v1 = *(const float4*)&embed[off + 4];
            bf16x8 p;
            p[0] = f2bf(v0.x); p[1] = f2bf(v0.y); p[2] = f2bf(v0.z); p[3] = f2bf(v0.w);
            p[4] = f2bf(v1.x); p[5] = f2bf(v1.y); p[6] = f2bf(v1.z); p[7] = f2bf(v1.w);
            *(bf16x8*)&embedB[off] = p;
        }
    } else {
        // ---- W transpose+convert, one 64x64 tile per block
        const int qq = q - 216;
        const int w = qq / 144, t = qq % 144;
        const int kt = t / 12, nt = t % 12;
        const float* src = (w == 0) ? W_corr
                         : (w == 1) ? W_corr + WSZ
                         : (w == 2) ? W_sh + WSZ
                                    : W_oh + WSZ;
        unsigned short* dst = WT + (size_t)w * WSZ;
        __shared__ float tile[64 * 65];
        const int r = tid >> 2, c4 = (tid & 3) * 16;
#pragma unroll
        for (int i = 0; i < 4; ++i) {
            float4 v = *(const float4*)&src[(size_t)(kt * 64 + r) * HD + nt * 64 + c4 + i * 4];
            tile[r * 65 + c4 + i * 4 + 0] = v.x;
            tile[r * 65 + c4 + i * 4 + 1] = v.y;
            tile[r * 65 + c4 + i * 4 + 2] = v.z;
            tile[r * 65 + c4 + i * 4 + 3] = v.w;
        }
        __syncthreads();
        bf16x8 p0, p1;
#pragma unroll
        for (int j = 0; j < 8; ++j) {
            p0[j] = f2bf(tile[(c4 + j) * 65 + r]);
            p1[j] = f2bf(tile[(c4 + 8 + j) * 65 + r]);
        }
        unsigned short* o = dst + (size_t)(nt * 64 + r) * HD + kt * 64 + c4;
        *(bf16x8*)(o)     = p0;
        *(bf16x8*)(o + 8) = p1;
    }
}

// ---------------------------------------------------------------------------
// Launch 2: biggemm. grid (27, 16), 256 threads. BK=64 (12 K-tiles, 2 barriers each).
//  x < 24: dual MFMA GEMM; x >= 24: relh blocks (48)
__global__ __launch_bounds__(256) void biggemm(
        const unsigned short* __restrict__ embedB,
        const unsigned short* __restrict__ WT,
        const float* __restrict__ biasrel,
        const float* __restrict__ W_st, const float* __restrict__ W_ot,
        const float* __restrict__ pool,
        const float* __restrict__ W_hr, const float* __restrict__ b_hr,
        float* __restrict__ AC, float* __restrict__ out_subj,
        float* __restrict__ out_obj, float* __restrict__ rh) {
    const int tid = threadIdx.x;

    if (blockIdx.x >= 24) {
        const int b = blockIdx.y >> 1;
        const int c = (blockIdx.x - 24) * 2 + (blockIdx.y & 1);
        __shared__ float prow[HD];
        __shared__ float rpart[4][64];
        for (int k = tid; k < HD; k += 256) prow[k] = pool[b * HD + k];
        __syncthreads();
        const int kc = tid >> 6, nn = tid & 63;
        const int n = c * 64 + nn;
        float acc = 0.f;
#pragma unroll 8
        for (int i = 0; i < 192; ++i) {
            const int k = kc * 192 + i;
            acc += prow[k] * W_hr[(size_t)k * H2D + n];
        }
        rpart[kc][nn] = acc;
        __syncthreads();
        if (kc == 0)
            rh[b * H2D + n] = fmaxf(rpart[0][nn] + rpart[1][nn] + rpart[2][nn] + rpart[3][nn] + b_hr[n], 0.f);
        return;
    }

    // stride 76 shorts: fr*38 words mod 32 distinct for fr=0..15 -> conflict-free b128
    __shared__ __align__(16) short As [64][76];
    __shared__ __align__(16) short Bs0[64][76];
    __shared__ __align__(16) short Bs1[64][76];
    __shared__ float partial[64][3];

    const int bn0 = blockIdx.x * 64;
    const int bm0 = blockIdx.y * 64;

    const unsigned short* W0 = (bn0 < HD) ? WT : WT + WSZ;
    const unsigned short* W1 = (bn0 < HD) ? WT + 2 * (size_t)WSZ : WT + 3 * (size_t)WSZ;
    const int col0 = (bn0 < HD) ? bn0 : bn0 - HD;

    if (tid < 192) partial[tid / 3][tid % 3] = 0.f;

    // staging: row = tid>>2 (0..63), kc8 = (tid&3)*8 (+32 second chunk)
    const int row = tid >> 2;
    const int kc8 = (tid & 3) * 8;

    const int lane = tid & 63;
    const int wv = tid >> 6;
    const int wm = (wv >> 1) * 32;
    const int wn = (wv & 1) * 32;
    const int fr = lane & 15;
    const int kq = (lane >> 4) * 8;
    const int mq = (lane >> 4) * 4;

    f32x4 c00 = {0.f,0.f,0.f,0.f}, c01 = c00, c10 = c00, c11 = c00;
    f32x4 h00 = c00, h01 = c00, h10 = c00, h11 = c00;

    for (int kt = 0; kt < 12; ++kt) {
        const int k0 = kt << 6;
        const size_t ea = (size_t)(bm0 + row) * HD + k0 + kc8;
        const size_t wa = (size_t)(col0 + row) * HD + k0 + kc8;
        bf16x8 av0 = *(const bf16x8*)&embedB[ea];
        bf16x8 av1 = *(const bf16x8*)&embedB[ea + 32];
        bf16x8 b0v0 = *(const bf16x8*)&W0[wa];
        bf16x8 b0v1 = *(const bf16x8*)&W0[wa + 32];
        bf16x8 b1v0 = *(const bf16x8*)&W1[wa];
        bf16x8 b1v1 = *(const bf16x8*)&W1[wa + 32];

        __syncthreads();
        *(bf16x8*)&As [row][kc8]      = av0;
        *(bf16x8*)&As [row][kc8 + 32] = av1;
        *(bf16x8*)&Bs0[row][kc8]      = b0v0;
        *(bf16x8*)&Bs0[row][kc8 + 32] = b0v1;
        *(bf16x8*)&Bs1[row][kc8]      = b1v0;
        *(bf16x8*)&Bs1[row][kc8 + 32] = b1v1;
        __syncthreads();

#pragma unroll
        for (int kk = 0; kk < 2; ++kk) {
            const int kx = kq + kk * 32;
            bf16x8 a0 = *(bf16x8*)&As[wm + fr][kx];
            bf16x8 a1 = *(bf16x8*)&As[wm + 16 + fr][kx];
            bf16x8 b0 = *(bf16x8*)&Bs0[wn + fr][kx];
            bf16x8 b1 = *(bf16x8*)&Bs0[wn + 16 + fr][kx];
            bf16x8 d0 = *(bf16x8*)&Bs1[wn + fr][kx];
            bf16x8 d1 = *(bf16x8*)&Bs1[wn + 16 + fr][kx];
            c00 = __builtin_amdgcn_mfma_f32_16x16x32_bf16(a0, b0, c00, 0, 0, 0);
            c01 = __builtin_amdgcn_mfma_f32_16x16x32_bf16(a0, b1, c01, 0, 0, 0);
            c10 = __builtin_amdgcn_mfma_f32_16x16x32_bf16(a1, b0, c10, 0, 0, 0);
            c11 = __builtin_amdgcn_mfma_f32_16x16x32_bf16(a1, b1, c11, 0, 0, 0);
            h00 = __builtin_amdgcn_mfma_f32_16x16x32_bf16(a0, d0, h00, 0, 0, 0);
            h01 = __builtin_amdgcn_mfma_f32_16x16x32_bf16(a0, d1, h01, 0, 0, 0);
            h10 = __builtin_amdgcn_mfma_f32_16x16x32_bf16(a1, d0, h10, 0, 0, 0);
            h11 = __builtin_amdgcn_mfma_f32_16x16x32_bf16(a1, d1, h11, 0, 0, 0);
        }
    }

    // GEMM0 epilogue: C/D layout col=lane&15, row=(lane>>4)*4+reg
#pragma unroll
    for (int i = 0; i < 2; ++i) {
#pragma unroll
        for (int j = 0; j < 2; ++j) {
            f32x4 a = (i == 0) ? (j == 0 ? c00 : c01) : (j == 0 ? c10 : c11);
            const int ncol = bn0 + wn + j * 16 + fr;
#pragma unroll
            for (int r = 0; r < 4; ++r) {
                const int mrow = bm0 + wm + i * 16 + mq + r;
                AC[(size_t)mrow * NF + ncol] = a[r];
            }
        }
    }

    // GEMM1 epilogue: relu(+biasrel), row-dot W_st/W_ot, atomics
    {
        const float* brl = biasrel + (size_t)(bm0 / LD) * NF;
        const float* Wt = (bn0 < HD) ? W_st : W_ot;
        float* op = (bn0 < HD) ? out_subj : out_obj;
        float pt[8][3] = {};
#pragma unroll
        for (int j = 0; j < 2; ++j) {
            const int ncol = bn0 + wn + j * 16 + fr;
            const int ncl = (bn0 < HD) ? ncol : ncol - HD;
            const float wt0 = Wt[ncl * 3 + 0];
            const float wt1 = Wt[ncl * 3 + 1];
            const float wt2 = Wt[ncl * 3 + 2];
            const float bias = brl[ncol];
#pragma unroll
            for (int i = 0; i < 2; ++i) {
                f32x4 a = (i == 0) ? (j == 0 ? h00 : h01) : (j == 0 ? h10 : h11);
#pragma unroll
                for (int r = 0; r < 4; ++r) {
                    const float v = fmaxf(a[r] + bias, 0.f);
                    pt[i * 4 + r][0] += v * wt0;
                    pt[i * 4 + r][1] += v * wt1;
                    pt[i * 4 + r][2] += v * wt2;
                }
            }
        }
#pragma unroll
        for (int mask = 1; mask < 16; mask <<= 1) {
#pragma unroll
            for (int x = 0; x < 8; ++x)
#pragma unroll
                for (int t = 0; t < 3; ++t)
                    pt[x][t] += __shfl_xor(pt[x][t], mask, 64);
        }
        if (fr == 0) {
#pragma unroll
            for (int i = 0; i < 2; ++i)
#pragma unroll
                for (int r = 0; r < 4; ++r)
#pragma unroll
                    for (int t = 0; t < 3; ++t)
                        atomicAdd(&partial[wm + i * 16 + mq + r][t], pt[i * 4 + r][t]);
        }
        __syncthreads();
        if (tid < 192) {
            const int m = tid / 3, t = tid % 3;
            atomicAdd(&op[(size_t)(bm0 + m) * 3 + t], partial[m][t]);
        }
    }
}

// ---------------------------------------------------------------------------
// Launch 3: corres + stage1. grid (33, 8), 512 threads (8 waves). (r11 shape)
__global__ __launch_bounds__(512) void corres_kernel(
        const float* __restrict__ AC,
        const float* __restrict__ b_corr, const float* __restrict__ W_gc,
        const float* __restrict__ b_gc,
        const float* __restrict__ rh,
        const float* __restrict__ W_rj, const float* __restrict__ b_rj,
        float* __restrict__ out, float* __restrict__ out_stage1) {
    const int b = blockIdx.y;
    const int tid = threadIdx.x;

    if (blockIdx.x == 32) {
        __shared__ float rl[H2D];
        __shared__ float spart[8][RD];
        if (tid < H2D) rl[tid] = rh[b * H2D + tid];
        __syncthreads();
        if (tid < 8 * RD) {
            const int n = tid % RD, kc = tid / RD;
            float acc = 0.f;
#pragma unroll 8
            for (int i = 0; i < 48; ++i) {
                const int k = kc * 48 + i;
                acc += rl[k] * W_rj[k * RD + n];
            }
            spart[kc][n] = acc;
        }
        __syncthreads();
        if (tid < RD) {
            float s = b_rj[tid];
#pragma unroll
            for (int q = 0; q < 8; ++q) s += spart[q][tid];
            out_stage1[b * RD + tid] = s;
        }
        return;
    }

    const int i0 = blockIdx.x * 4;
    const int lane = tid & 63;
    const int wave = tid >> 6;  // 0..7

    f32x4 wg[3], cb[4][3];
#pragma unroll
    for (int s = 0; s < 3; ++s) {
        const int h = s * 256 + lane * 4;
        f32x4 w  = *(const f32x4*)&W_gc[h];
        f32x4 bc = *(const f32x4*)&b_corr[h];
        wg[s] = w;
#pragma unroll
        for (int i = 0; i < 4; ++i) {
            f32x4 cv = *(const f32x4*)&AC[((size_t)(b * LD + i0 + i)) * NF + HD + h];
            cb[i][s] = cv + bc;
        }
    }
    const float bg = b_gc[0];

    f32x4 a[3];
    {
        const float* ar = AC + ((size_t)(b * LD + wave)) * NF;
#pragma unroll
        for (int s = 0; s < 3; ++s) a[s] = *(const f32x4*)&ar[s * 256 + lane * 4];
    }
    for (int j = wave; j < LD; j += 8) {
        f32x4 an[3];
        if (j + 8 < LD) {
            const float* ar = AC + ((size_t)(b * LD + j + 8)) * NF;
#pragma unroll
            for (int s = 0; s < 3; ++s) an[s] = *(const f32x4*)&ar[s * 256 + lane * 4];
        }
        f32x4 sv[4];
#pragma unroll
        for (int i = 0; i < 4; ++i) sv[i] = (f32x4){0.f, 0.f, 0.f, 0.f};
#pragma unroll
        for (int s = 0; s < 3; ++s) {
#pragma unroll
            for (int i = 0; i < 4; ++i)
                sv[i] += vmax0(a[s] + cb[i][s]) * wg[s];
        }
#pragma unroll
        for (int i = 0; i < 4; ++i) {
            float r = (sv[i][0] + sv[i][1]) + (sv[i][2] + sv[i][3]);
#pragma unroll
            for (int off = 32; off > 0; off >>= 1) r += __shfl_down(r, off, 64);
            if (lane == 0)
                out[((size_t)(b * LD + i0 + i)) * LD + j] = r + bg;
        }
#pragma unroll
        for (int s = 0; s < 3; ++s) a[s] = an[s];
    }
}

// ---------------------------------------------------------------------------
extern "C" void kernel_launch(void* const* d_in, const int* in_sizes, int n_in,
                              void* d_out, int out_size, void* d_ws, size_t ws_size,
                              hipStream_t stream) {
    const float* embed   = (const float*)d_in[0];
    const float* mask    = (const float*)d_in[1];
    const int*   trel    = (const int*)d_in[2];
    const float* W_hr    = (const float*)d_in[3];
    const float* b_hr    = (const float*)d_in[4];
    const float* W_rj    = (const float*)d_in[5];
    const float* b_rj    = (const float*)d_in[6];
    const float* rel_emb = (const float*)d_in[7];
    const float* W_corr  = (const float*)d_in[8];
    const float* b_corr  = (const float*)d_in[9];
    const float* W_gc    = (const float*)d_in[10];
    const float* b_gc    = (const float*)d_in[11];
    const float* W_sh    = (const float*)d_in[12];
    const float* b_sh    = (const float*)d_in[13];
    const float* W_st    = (const float*)d_in[14];
    const float* b_st    = (const float*)d_in[15];
    const float* W_oh    = (const float*)d_in[16];
    const float* b_oh    = (const float*)d_in[17];
    const float* W_ot    = (const float*)d_in[18];
    const float* b_ot    = (const float*)d_in[19];
    float* out = (float*)d_out;

    float* ws      = (float*)d_ws;
    float* AC      = ws;                             // 1,572,864 floats
    float* biasrel = ws + 1572864;                   // 12,288
    float* rh      = ws + 1572864 + 12288;           // 3,072
    float* pool    = ws + 1572864 + 12288 + 3072;    // 6,144
    unsigned short* embedB = (unsigned short*)(ws + 1594368);          // 786,432 shorts
    unsigned short* WT     = (unsigned short*)(ws + 1594368 + 393216); // 4*589,824 shorts

    // Output layout: stage1[192] | subj[3072] | obj[3072] | pred_corres[131072]
    float* out_stage1 = out;
    float* out_subj   = out + 192;
    float* out_obj    = out + 3264;
    float* out_corr   = out + 6336;

    prep_kernel<<<792, 256, 0, stream>>>(embed, mask, rel_emb, trel, W_corr,
                                         W_sh, b_sh, W_oh, b_oh, b_st, b_ot,
                                         pool, biasrel, embedB, WT,
                                         out_subj, out_obj);

    biggemm<<<dim3(27, 16), 256, 0, stream>>>(embedB, WT, biasrel, W_st, W_ot,
                                              pool, W_hr, b_hr,
                                              AC, out_subj, out_obj, rh);

    corres_kernel<<<dim3(33, BD), 512, 0, stream>>>(AC, b_corr, W_gc, b_gc,
                                                    rh, W_rj, b_rj, out_corr, out_stage1);
}